// Round 8
// baseline (226.717 us; speedup 1.0000x reference)
//
#include <hip/hip_runtime.h>
#include <hip/hip_bf16.h>
#include <stdint.h>

// Problem constants (N,C,H,W = 4,128,64,64)
#define NB 4
#define CH 128
#define LL 4096   // H*W

typedef __attribute__((ext_vector_type(8))) short short8;   // 8 bf16 MFMA A/B frag
typedef __attribute__((ext_vector_type(4))) short short4b;  // 4 bf16 (8B)
typedef __attribute__((ext_vector_type(4))) float floatx4;  // 16x16 C/D frag
typedef __attribute__((ext_vector_type(16))) float floatx16; // 32x32 C/D frag

static __device__ __forceinline__ short f2bf(float f) {
    uint32_t u = __float_as_uint(f);
    u += 0x7fffu + ((u >> 16) & 1u);
    return (short)(u >> 16);
}

// ---------------------------------------------------------------------------
// Kernel 1: QKV projection (unchanged from R7). Qt[n][l][c], Kt[n][l][c]
// (K pre-scaled 1/sqrt(C)), V in panel layout Vp[n][l>>4][c][l&15].
// ---------------------------------------------------------------------------
__global__ __launch_bounds__(256) void proj_kernel(
    const float* __restrict__ x,
    const float* __restrict__ Wq, const float* __restrict__ bq,
    const float* __restrict__ Wk, const float* __restrict__ bk,
    const float* __restrict__ Wv, const float* __restrict__ bv,
    short* __restrict__ Qt, short* __restrict__ Kt, short* __restrict__ Vp)
{
    const int b   = blockIdx.x;
    const int n   = b >> 8;
    const int rem = b & 255;
    const int o0  = (rem >> 4) * 8;
    const int l   = ((rem & 15) << 8) + threadIdx.x;

    const float* xp = x + ((size_t)n * CH) * LL + l;

    float aq[8], ak[8], av[8];
    #pragma unroll
    for (int u = 0; u < 8; ++u) {
        aq[u] = bq[o0 + u];
        ak[u] = bk[o0 + u];
        av[u] = bv[o0 + u];
    }

    #pragma unroll 4
    for (int c = 0; c < CH; ++c) {
        const float xv = xp[(size_t)c * LL];
        #pragma unroll
        for (int u = 0; u < 8; ++u) {
            aq[u] += Wq[(o0 + u) * CH + c] * xv;
            ak[u] += Wk[(o0 + u) * CH + c] * xv;
            av[u] += Wv[(o0 + u) * CH + c] * xv;
        }
    }

    const float scale = 0.08838834764831845f;  // 1/sqrt(128), folded into K
    short8 q0, k0;
    #pragma unroll
    for (int u = 0; u < 8; ++u) {
        q0[u] = f2bf(aq[u]);
        k0[u] = f2bf(ak[u] * scale);
    }
    *(short8*)(void*)(Qt + ((size_t)n * LL + l) * CH + o0) = q0;
    *(short8*)(void*)(Kt + ((size_t)n * LL + l) * CH + o0) = k0;
    short* vpan = Vp + ((size_t)n * 256 + (l >> 4)) * 2048 + (l & 15);
    #pragma unroll
    for (int u = 0; u < 8; ++u)
        vpan[(o0 + u) * 16] = f2bf(av[u]);
}

// ---------------------------------------------------------------------------
// Kernel 2: softmax denominators (S^T tiles, A=Q resident, B=K staged).
// NOW: K double-buffered in LDS -> ONE barrier per step (was 2).
// grid = 4*64*2 = 512 (2 blocks/CU), 512 thr. atomicAdd into zeroed Dsum.
// ---------------------------------------------------------------------------
__global__ __launch_bounds__(512, 2) void rowsum_kernel(
    const short* __restrict__ Qt, const short* __restrict__ Kt,
    float* __restrict__ Dsum)
{
    const int b    = blockIdx.x;
    const int n    = b >> 7;
    const int rem  = b & 127;
    const int m0   = (rem >> 1) << 6;
    const int lh   = rem & 1;
    const int tid  = threadIdx.x;
    const int wave = tid >> 6;
    const int lane = tid & 63;
    const int quad = lane >> 4;
    const int mc   = lane & 15;

    __shared__ short Kbuf[2][128][136];   // dbuf [l][c] +8 pad (69.6 KB)

    const short* Qn = Qt + (size_t)n * LL * CH;
    const short* Kn = Kt + (size_t)n * LL * CH + (size_t)lh * 2048 * CH;

    // resident Q A-frags: A[m=m0+16mst+mc][k=32s+8q+j]
    short8 qf[4][4];
    #pragma unroll
    for (int mst = 0; mst < 4; ++mst)
        #pragma unroll
        for (int s = 0; s < 4; ++s)
            qf[mst][s] = *(const short8*)(const void*)(
                Qn + (size_t)(m0 + 16 * mst + mc) * CH + 32 * s + quad * 8);

    const int srow = tid >> 4, sch = tid & 15;
    short8 kreg[4];
    #pragma unroll
    for (int i = 0; i < 4; ++i)
        kreg[i] = *(const short8*)(const void*)(
            Kn + (size_t)(i * 32 + srow) * CH + sch * 8);

    // stage tile 0, prefetch tile 1
    #pragma unroll
    for (int i = 0; i < 4; ++i)
        *(short8*)(void*)&Kbuf[0][i * 32 + srow][sch * 8] = kreg[i];
    #pragma unroll
    for (int i = 0; i < 4; ++i)
        kreg[i] = *(const short8*)(const void*)(
            Kn + (size_t)(128 + i * 32 + srow) * CH + sch * 8);
    __syncthreads();

    for (int step = 0; step < 16; ++step) {
        const int lb = step << 7;
        const int p  = step & 1;

        // B-frags from current buffer: B[k=32s+8q+j][col=l=16*wave+mc]
        short8 kfr[4];
        #pragma unroll
        for (int s = 0; s < 4; ++s)
            kfr[s] = *(const short8*)(const void*)&Kbuf[p][16 * wave + mc][32 * s + quad * 8];

        // stage next tile into other buffer; prefetch tile step+2
        if (step < 15) {
            #pragma unroll
            for (int i = 0; i < 4; ++i)
                *(short8*)(void*)&Kbuf[p ^ 1][i * 32 + srow][sch * 8] = kreg[i];
            if (step < 14) {
                const short* Ks = Kn + (size_t)(lb + 256) * CH;
                #pragma unroll
                for (int i = 0; i < 4; ++i)
                    kreg[i] = *(const short8*)(const void*)(
                        Ks + (size_t)(i * 32 + srow) * CH + sch * 8);
            }
        }

        float rsum = 0.f;
        #pragma unroll
        for (int mst = 0; mst < 4; ++mst) {
            floatx4 a = {0.f, 0.f, 0.f, 0.f};
            #pragma unroll
            for (int s = 0; s < 4; ++s)
                a = __builtin_amdgcn_mfma_f32_16x16x32_bf16(qf[mst][s], kfr[s], a, 0, 0, 0);
            #pragma unroll
            for (int r = 0; r < 4; ++r) rsum += __expf(a[r]);
        }
        rsum += __shfl_xor(rsum, 16);
        rsum += __shfl_xor(rsum, 32);
        if (lane < 16)
            atomicAdd(&Dsum[(size_t)n * LL + lh * 2048 + lb + 16 * wave + lane], rsum);

        __syncthreads();   // single barrier: next iter reads buf p^1
    }
}

// ---------------------------------------------------------------------------
// Kernel 3: O[c,m] = sum_l V[c,l]*exp(S[l,m])/D[l].
// l-split (lsh=1 -> 2 halves): grid = 4*64*2 = 512 (2 blocks/CU), 16 steps.
// direct=1 (fallback, lsh=0): grid 256, writes out = x + O itself.
// Reciprocal of Dsum computed inline (rcp kernel removed).
// ---------------------------------------------------------------------------
__global__ __launch_bounds__(512, 2) void attn_out_kernel(
    const short* __restrict__ Qt, const short* __restrict__ Kt,
    const short* __restrict__ Vp, const float* __restrict__ Dsum,
    const float* __restrict__ x, float* __restrict__ out,
    float* __restrict__ Opart, int lsh, int direct)
{
    const int b     = blockIdx.x;
    const int n     = b >> (6 + lsh);
    const int r_    = b & ((64 << lsh) - 1);
    const int ls    = r_ >> 6;
    const int m0    = (r_ & 63) << 6;
    const int lbase = ls << (12 - lsh);
    const int nsteps = 32 >> lsh;
    const int tid  = threadIdx.x;
    const int wave = tid >> 6;        // 0..7
    const int lane = tid & 63;
    const int quad = lane >> 4;
    const int mc   = lane & 15;
    const int l32  = lane & 31;
    const int h    = lane >> 5;
    const int ct   = wave & 3;        // c-tile (32 channels)
    const int mh   = wave >> 2;       // m-half (32 cols)

    __shared__ short Kbuf[128][136];  // [l][c] +8 pad (34.8 KB)
    __shared__ short P[64][136];      // [m][l] +8 pad (17.4 KB)

    const short* Qn  = Qt + (size_t)n * LL * CH;
    const short* Kn  = Kt + ((size_t)n * LL + lbase) * CH;
    const short* Vpn = Vp + (size_t)n * 524288;
    const float* Dn  = Dsum + (size_t)n * LL;

    // resident Q B-frags: B[k=c][col=m]
    short8 qf[4][4];
    #pragma unroll
    for (int mst = 0; mst < 4; ++mst)
        #pragma unroll
        for (int s = 0; s < 4; ++s)
            qf[mst][s] = *(const short8*)(const void*)(
                Qn + (size_t)(m0 + 16 * mst + mc) * CH + 32 * s + quad * 8);

    const int srow = tid >> 4, sch = tid & 15;
    short8 kreg[4];
    #pragma unroll
    for (int i = 0; i < 4; ++i)
        kreg[i] = *(const short8*)(const void*)(
            Kn + (size_t)(i * 32 + srow) * CH + sch * 8);

    floatx16 acc;
    #pragma unroll
    for (int r = 0; r < 16; ++r) acc[r] = 0.f;

    for (int step = 0; step < nsteps; ++step) {
        const int lb = lbase + (step << 7);      // global l base
        const int lo = step << 7;                // local offset in Kn

        // V A-frags: coalesced panel loads
        short8 vf[8];
        #pragma unroll
        for (int kc = 0; kc < 8; ++kc)
            vf[kc] = *(const short8*)(const void*)(
                Vpn + (size_t)((lb >> 4) + kc) * 2048 + (32 * ct + l32) * 16 + 8 * h);

        // stage K tile, prefetch next
        #pragma unroll
        for (int i = 0; i < 4; ++i)
            *(short8*)(void*)&Kbuf[i * 32 + srow][sch * 8] = kreg[i];
        if (step < nsteps - 1) {
            const short* Ks = Kn + (size_t)(lo + 128) * CH;
            #pragma unroll
            for (int i = 0; i < 4; ++i)
                kreg[i] = *(const short8*)(const void*)(
                    Ks + (size_t)(i * 32 + srow) * CH + sch * 8);
        }
        __syncthreads();   // B1: Kbuf visible

        // ---- phase A: S stripe [16 l] x [64 m] -> P ----
        {
            short8 kfr[4];
            #pragma unroll
            for (int s = 0; s < 4; ++s)
                kfr[s] = *(const short8*)(const void*)&Kbuf[16 * wave + mc][32 * s + quad * 8];
            const floatx4 ds = *(const floatx4*)(const void*)(Dn + lb + 16 * wave + quad * 4);
            float d[4];
            #pragma unroll
            for (int r = 0; r < 4; ++r) d[r] = 1.0f / ds[r];
            #pragma unroll
            for (int mst = 0; mst < 4; ++mst) {
                floatx4 sa = {0.f, 0.f, 0.f, 0.f};
                #pragma unroll
                for (int s = 0; s < 4; ++s)
                    sa = __builtin_amdgcn_mfma_f32_16x16x32_bf16(kfr[s], qf[mst][s], sa, 0, 0, 0);
                short4b pv;
                #pragma unroll
                for (int r = 0; r < 4; ++r) pv[r] = f2bf(__expf(sa[r]) * d[r]);
                *(short4b*)(void*)&P[16 * mst + mc][16 * wave + quad * 4] = pv;
            }
        }
        __syncthreads();   // B2: P visible

        // ---- phase B: bulk-load pf, release LDS, then MFMA ----
        short8 pf[8];
        #pragma unroll
        for (int kc = 0; kc < 8; ++kc)
            pf[kc] = *(const short8*)(const void*)&P[32 * mh + l32][16 * kc + 8 * h];
        __syncthreads();   // B3: LDS reads done

        #pragma unroll
        for (int kc = 0; kc < 8; ++kc)
            acc = __builtin_amdgcn_mfma_f32_32x32x16_bf16(vf[kc], pf[kc], acc, 0, 0, 0);
    }

    // ---- epilogue (32x32 C-layout) ----
    #pragma unroll
    for (int r = 0; r < 16; ++r) {
        const int c = 32 * ct + (r & 3) + 8 * (r >> 2) + 4 * h;
        const int m = m0 + 32 * mh + l32;
        const size_t idx = ((size_t)n * CH + c) * LL + m;
        if (direct) out[idx] = x[idx] + acc[r];
        else        Opart[(size_t)ls * (NB * CH * LL) + idx] = acc[r];
    }
}

// ---------------------------------------------------------------------------
// Kernel 4: out = x + O0 + O1  (float4, 2048 blocks x 256 thr)
// ---------------------------------------------------------------------------
__global__ __launch_bounds__(256) void combine_kernel(
    const float* __restrict__ x, const float* __restrict__ O0,
    const float* __restrict__ O1, float* __restrict__ out)
{
    const int g = blockIdx.x * 256 + threadIdx.x;   // 0..524287 (float4)
    const floatx4 xv = ((const floatx4*)x)[g];
    const floatx4 a  = ((const floatx4*)O0)[g];
    const floatx4 b  = ((const floatx4*)O1)[g];
    floatx4 o;
    #pragma unroll
    for (int i = 0; i < 4; ++i) o[i] = xv[i] + a[i] + b[i];
    ((floatx4*)out)[g] = o;
}

// ---------------------------------------------------------------------------
extern "C" void kernel_launch(void* const* d_in, const int* in_sizes, int n_in,
                              void* d_out, int out_size, void* d_ws, size_t ws_size,
                              hipStream_t stream) {
    (void)in_sizes; (void)n_in; (void)out_size;
    const float* x  = (const float*)d_in[0];
    const float* Wq = (const float*)d_in[1];
    const float* bq = (const float*)d_in[2];
    const float* Wk = (const float*)d_in[3];
    const float* bk = (const float*)d_in[4];
    const float* Wv = (const float*)d_in[5];
    const float* bv = (const float*)d_in[6];
    float* out = (float*)d_out;

    char* ws = (char*)d_ws;
    // ws: Qt 4MB | Kt 4MB | Vp 4MB | Dsum 64KB | O0 8MB | O1 8MB (~28.1 MB)
    short* Qt = (short*)(ws);
    short* Kt = (short*)(ws + 4194304);
    short* Vp = (short*)(ws + 8388608);
    float* Ds = (float*)(ws + 12582912);
    float* O0 = (float*)(ws + 12648448);
    float* O1 = (float*)(ws + 21037056);
    const size_t need_split = 29425664;   // end of O1

    const int use_split = (ws_size >= need_split) ? 1 : 0;  // constant per run

    hipMemsetAsync(Ds, 0, 65536, stream);
    proj_kernel<<<1024, 256, 0, stream>>>(x, Wq, bq, Wk, bk, Wv, bv, Qt, Kt, Vp);
    rowsum_kernel<<<512, 512, 0, stream>>>(Qt, Kt, Ds);
    if (use_split) {
        attn_out_kernel<<<512, 512, 0, stream>>>(Qt, Kt, Vp, Ds, x, out, O0, 1, 0);
        combine_kernel<<<2048, 256, 0, stream>>>(x, O0, O1, out);
    } else {
        attn_out_kernel<<<256, 512, 0, stream>>>(Qt, Kt, Vp, Ds, x, out, O0, 0, 1);
    }
}

// Round 9
// 213.068 us; speedup vs baseline: 1.0641x; 1.0641x over previous
//
#include <hip/hip_runtime.h>
#include <hip/hip_bf16.h>
#include <stdint.h>

// Problem constants (N,C,H,W = 4,128,64,64)
#define NB 4
#define CH 128
#define LL 4096   // H*W

typedef __attribute__((ext_vector_type(8))) short short8;   // 8 bf16 MFMA A/B frag
typedef __attribute__((ext_vector_type(4))) short short4b;  // 4 bf16 (8B)
typedef __attribute__((ext_vector_type(4))) float floatx4;  // 16x16 C/D frag
typedef __attribute__((ext_vector_type(16))) float floatx16; // 32x32 C/D frag

// Frag-major layout for Q,K: element (n,l,c) ->
//   (n*256 + (l>>4))*2048 + (c>>5)*512 + ((c>>3)&3)*128 + (l&15)*8 + (c&7)
// A 16x16x32 frag (tile t, k-slice s) is 512 contiguous shorts at
// (n*256+t)*2048 + s*512, and lane L reads shorts [8L, 8L+8) — one fully
// coalesced 16B/lane global load; identical mapping serves A- and B-frags.

static __device__ __forceinline__ short f2bf(float f) {
    uint32_t u = __float_as_uint(f);
    u += 0x7fffu + ((u >> 16) & 1u);
    return (short)(u >> 16);
}

// ---------------------------------------------------------------------------
// Kernel 1: QKV projection. Writes Qf/Kf frag-major (K pre-scaled 1/sqrt(C)),
// V in panel layout Vp[n][l>>4][c][l&15].
// ---------------------------------------------------------------------------
__global__ __launch_bounds__(256) void proj_kernel(
    const float* __restrict__ x,
    const float* __restrict__ Wq, const float* __restrict__ bq,
    const float* __restrict__ Wk, const float* __restrict__ bk,
    const float* __restrict__ Wv, const float* __restrict__ bv,
    short* __restrict__ Qf, short* __restrict__ Kf, short* __restrict__ Vp)
{
    const int b   = blockIdx.x;
    const int n   = b >> 8;
    const int rem = b & 255;
    const int o0  = (rem >> 4) * 8;
    const int l   = ((rem & 15) << 8) + threadIdx.x;

    const float* xp = x + ((size_t)n * CH) * LL + l;

    float aq[8], ak[8], av[8];
    #pragma unroll
    for (int u = 0; u < 8; ++u) {
        aq[u] = bq[o0 + u];
        ak[u] = bk[o0 + u];
        av[u] = bv[o0 + u];
    }

    #pragma unroll 4
    for (int c = 0; c < CH; ++c) {
        const float xv = xp[(size_t)c * LL];
        #pragma unroll
        for (int u = 0; u < 8; ++u) {
            aq[u] += Wq[(o0 + u) * CH + c] * xv;
            ak[u] += Wk[(o0 + u) * CH + c] * xv;
            av[u] += Wv[(o0 + u) * CH + c] * xv;
        }
    }

    const float scale = 0.08838834764831845f;  // 1/sqrt(128), folded into K
    short8 q0, k0;
    #pragma unroll
    for (int u = 0; u < 8; ++u) {
        q0[u] = f2bf(aq[u]);
        k0[u] = f2bf(ak[u] * scale);
    }
    // frag-major store: 16B per thread, coalesced within each 16-l group
    const size_t fbase = ((size_t)n * 256 + (l >> 4)) * 2048
                       + (size_t)(o0 >> 5) * 512 + (size_t)((o0 >> 3) & 3) * 128
                       + (size_t)(l & 15) * 8;
    *(short8*)(void*)(Qf + fbase) = q0;
    *(short8*)(void*)(Kf + fbase) = k0;
    short* vpan = Vp + ((size_t)n * 256 + (l >> 4)) * 2048 + (l & 15);
    #pragma unroll
    for (int u = 0; u < 8; ++u)
        vpan[(o0 + u) * 16] = f2bf(av[u]);
}

// ---------------------------------------------------------------------------
// Kernel 2: softmax denominators. NO LDS, NO barriers. grid = 4n*256lt*...:
// 1024 blocks x 256 thr (4 blocks/CU); wave = (l-tile of 16, m-quarter).
// K A-frags resident; Q B-frags streamed coalesced from frag-major Qf.
// atomicAdd partials into zeroed Dsum.
// ---------------------------------------------------------------------------
__global__ __launch_bounds__(256, 4) void rowsum_kernel(
    const short* __restrict__ Qf, const short* __restrict__ Kf,
    float* __restrict__ Dsum)
{
    const int b    = blockIdx.x;
    const int n    = b >> 8;
    const int lt   = b & 255;            // l-tile of 16
    const int wave = threadIdx.x >> 6;   // m-quarter
    const int lane = threadIdx.x & 63;
    const int quad = lane >> 4;
    const int mc   = lane & 15;

    const short* Kb = Kf + ((size_t)n * 256 + lt) * 2048 + lane * 8;
    short8 kf[4];
    #pragma unroll
    for (int s = 0; s < 4; ++s) kf[s] = *(const short8*)(const void*)(Kb + s * 512);

    const short* Qn = Qf + (size_t)n * 524288 + lane * 8;
    float rs[4] = {0.f, 0.f, 0.f, 0.f};

    // 64 Q-tiles (m) per wave, 2 ILP chains
    for (int i = 0; i < 64; i += 2) {
        const short* qa = Qn + (size_t)(wave * 64 + i) * 2048;
        const short* qb = qa + 2048;
        floatx4 a0 = {0.f, 0.f, 0.f, 0.f};
        floatx4 a1 = {0.f, 0.f, 0.f, 0.f};
        #pragma unroll
        for (int s = 0; s < 4; ++s) {
            a0 = __builtin_amdgcn_mfma_f32_16x16x32_bf16(
                kf[s], *(const short8*)(const void*)(qa + s * 512), a0, 0, 0, 0);
            a1 = __builtin_amdgcn_mfma_f32_16x16x32_bf16(
                kf[s], *(const short8*)(const void*)(qb + s * 512), a1, 0, 0, 0);
        }
        #pragma unroll
        for (int r = 0; r < 4; ++r) rs[r] += __expf(a0[r]) + __expf(a1[r]);
    }

    // sum over the 16 column-lanes (C-layout col = lane&15 = m)
    #pragma unroll
    for (int r = 0; r < 4; ++r) {
        float v = rs[r];
        v += __shfl_xor(v, 1);
        v += __shfl_xor(v, 2);
        v += __shfl_xor(v, 4);
        v += __shfl_xor(v, 8);
        rs[r] = v;
    }
    if (mc == 0) {
        #pragma unroll
        for (int r = 0; r < 4; ++r)   // l = 16*lt + quad*4 + r
            atomicAdd(&Dsum[(size_t)n * LL + 16 * lt + quad * 4 + r], rs[r]);
    }
}

// ---------------------------------------------------------------------------
// Kernel 3: O[c,m] = sum_l V[c,l]*exp(S[l,m])/D[l];  out = x + O.
// grid = 4n * 128 m-blocks(32) = 512 blocks x 512 thr (2 blocks/CU).
// No K staging: phase-A A-frags load coalesced from frag-major Kf.
// LDS: P[32 m][128 l] (8.7 KB) + 16 KB reduce scratch. 2 barriers/step.
// Phase B: wave w: ct=w&3 (32 channels), kh=w>>2 splits kc; final cross-
// pair reduce via LDS once.
// ---------------------------------------------------------------------------
__global__ __launch_bounds__(512, 4) void attn_out_kernel(
    const short* __restrict__ Qf, const short* __restrict__ Kf,
    const short* __restrict__ Vp, const float* __restrict__ Dsum,
    const float* __restrict__ x, float* __restrict__ out)
{
    const int b    = blockIdx.x;
    const int n    = b >> 7;
    const int m0   = (b & 127) << 5;    // m-block of 32
    const int tid  = threadIdx.x;
    const int wave = tid >> 6;          // 0..7
    const int lane = tid & 63;
    const int quad = lane >> 4;
    const int mc   = lane & 15;
    const int l32  = lane & 31;
    const int h    = lane >> 5;
    const int ct   = wave & 3;          // c-tile (32 channels)
    const int kh   = wave >> 2;         // kc-half

    __shared__ short P[32][136];        // [m][l] +8 pad (8.7 KB)
    __shared__ float Rbuf[4][64][16];   // cross-pair reduce scratch (16 KB)

    const short* Qn  = Qf + (size_t)n * 524288;
    const short* Kn  = Kf + (size_t)n * 524288;
    const short* Vpn = Vp + (size_t)n * 524288;
    const float* Dn  = Dsum + (size_t)n * LL;

    // resident Q B-frags (2 m-tiles x 4 slices), coalesced frag loads
    short8 qf[2][4];
    #pragma unroll
    for (int mst = 0; mst < 2; ++mst)
        #pragma unroll
        for (int s = 0; s < 4; ++s)
            qf[mst][s] = *(const short8*)(const void*)(
                Qn + (size_t)((m0 >> 4) + mst) * 2048 + s * 512 + lane * 8);

    floatx16 acc;
    #pragma unroll
    for (int r = 0; r < 16; ++r) acc[r] = 0.f;

    for (int step = 0; step < 32; ++step) {
        const int lb = step << 7;

        // ---- phase A: wave w computes S rows [lb+16w..+16) x 32 m ----
        short8 kfr[4];
        #pragma unroll
        for (int s = 0; s < 4; ++s)
            kfr[s] = *(const short8*)(const void*)(
                Kn + (size_t)(step * 8 + wave) * 2048 + s * 512 + lane * 8);
        const floatx4 ds = *(const floatx4*)(const void*)(Dn + lb + 16 * wave + quad * 4);
        float d[4];
        #pragma unroll
        for (int r = 0; r < 4; ++r) d[r] = 1.0f / ds[r];

        #pragma unroll
        for (int mst = 0; mst < 2; ++mst) {
            floatx4 sa = {0.f, 0.f, 0.f, 0.f};
            #pragma unroll
            for (int s = 0; s < 4; ++s)
                sa = __builtin_amdgcn_mfma_f32_16x16x32_bf16(kfr[s], qf[mst][s], sa, 0, 0, 0);
            short4b pv;
            #pragma unroll
            for (int r = 0; r < 4; ++r) pv[r] = f2bf(__expf(sa[r]) * d[r]);
            // C-layout (row=l=4q+r, col=m=mc) -> P[m][l-local]
            *(short4b*)(void*)&P[16 * mst + mc][16 * wave + quad * 4] = pv;
        }
        __syncthreads();   // B1: P visible

        // ---- phase B: V panel x P, kc-half per wave ----
        short8 vf[4], pf[4];
        #pragma unroll
        for (int i = 0; i < 4; ++i) {
            const int kc = kh * 4 + i;
            vf[i] = *(const short8*)(const void*)(
                Vpn + (size_t)((lb >> 4) + kc) * 2048 + (32 * ct + l32) * 16 + 8 * h);
            pf[i] = *(const short8*)(const void*)&P[l32][16 * kc + 8 * h];
        }
        __syncthreads();   // B2: P reads done -> next step may overwrite

        #pragma unroll
        for (int i = 0; i < 4; ++i)
            acc = __builtin_amdgcn_mfma_f32_32x32x16_bf16(vf[i], pf[i], acc, 0, 0, 0);
    }

    // ---- cross-pair (kh) reduce ----
    if (kh == 1)
        *(floatx16*)(void*)&Rbuf[ct][lane][0] = acc;
    __syncthreads();
    if (kh == 0) {
        const floatx16 o = *(const floatx16*)(const void*)&Rbuf[ct][lane][0];
        #pragma unroll
        for (int r = 0; r < 16; ++r) {
            const int c = 32 * ct + (r & 3) + 8 * (r >> 2) + 4 * h;
            const int m = m0 + l32;
            const size_t idx = ((size_t)n * CH + c) * LL + m;
            out[idx] = x[idx] + acc[r] + o[r];
        }
    }
}

// ---------------------------------------------------------------------------
extern "C" void kernel_launch(void* const* d_in, const int* in_sizes, int n_in,
                              void* d_out, int out_size, void* d_ws, size_t ws_size,
                              hipStream_t stream) {
    (void)in_sizes; (void)n_in; (void)out_size; (void)ws_size;
    const float* x  = (const float*)d_in[0];
    const float* Wq = (const float*)d_in[1];
    const float* bq = (const float*)d_in[2];
    const float* Wk = (const float*)d_in[3];
    const float* bk = (const float*)d_in[4];
    const float* Wv = (const float*)d_in[5];
    const float* bv = (const float*)d_in[6];
    float* out = (float*)d_out;

    char* ws = (char*)d_ws;
    // ws: Qf 4MB | Kf 4MB | Vp 4MB | Dsum 64KB  (~12.65 MB)
    short* Qf = (short*)(ws);
    short* Kf = (short*)(ws + 4194304);
    short* Vp = (short*)(ws + 8388608);
    float* Ds = (float*)(ws + 12582912);

    hipMemsetAsync(Ds, 0, 65536, stream);
    proj_kernel<<<1024, 256, 0, stream>>>(x, Wq, bq, Wk, bk, Wv, bv, Qf, Kf, Vp);
    rowsum_kernel<<<1024, 256, 0, stream>>>(Qf, Kf, Ds);
    attn_out_kernel<<<512, 512, 0, stream>>>(Qf, Kf, Vp, Ds, x, out);
}